// Round 1
// baseline (429.704 us; speedup 1.0000x reference)
//
#include <hip/hip_runtime.h>

// 2D single-level Haar DWT, quadrants packed into channels.
// x: (8, 512, 512, 32) f32  ->  out: (8, 256, 256, 128) f32
// out[b, i1, i2, q*32+c] from 2x2 block of x at (2*i1, 2*i2).

static constexpr int N_    = 512;
static constexpr int HALF_ = 256;
static constexpr int C_    = 32;
static constexpr int B_    = 8;

__global__ __launch_bounds__(256)
void dwt2d_haar(const float* __restrict__ x, float* __restrict__ out) {
    // t = ((b*256 + i1)*256 + i2)*8 + cv   (cv = float4 group within 32 chans)
    const size_t t  = (size_t)blockIdx.x * 256 + threadIdx.x;
    const int    cv = (int)(t & 7);
    const size_t p  = t >> 3;
    const int    i2 = (int)(p & 255);
    const size_t pq = p >> 8;
    const int    i1 = (int)(pq & 255);
    const int    b  = (int)(pq >> 8);

    const size_t row_stride = (size_t)N_ * C_;  // 16384 floats per input row
    const size_t in_base = ((size_t)b * N_ + 2 * i1) * row_stride
                         + (size_t)(2 * i2) * C_ + (size_t)cv * 4;

    const float4 va = *reinterpret_cast<const float4*>(x + in_base);                    // (2i1  , 2i2  )
    const float4 vb = *reinterpret_cast<const float4*>(x + in_base + C_);               // (2i1  , 2i2+1)
    const float4 vc = *reinterpret_cast<const float4*>(x + in_base + row_stride);       // (2i1+1, 2i2  )
    const float4 vd = *reinterpret_cast<const float4*>(x + in_base + row_stride + C_);  // (2i1+1, 2i2+1)

    float4 ll, lh, hl, hh;
    #define DO_COMP(f)                                          \
        ll.f = 0.5f * ((va.f + vb.f) + (vc.f + vd.f));          \
        lh.f = 0.5f * ((vc.f + vd.f) - (va.f + vb.f));          \
        hl.f = 0.5f * ((vb.f - va.f) + (vd.f - vc.f));          \
        hh.f = 0.5f * ((va.f - vb.f) - (vc.f - vd.f));
    DO_COMP(x) DO_COMP(y) DO_COMP(z) DO_COMP(w)
    #undef DO_COMP

    // out pixel: 128 contiguous floats; quadrant q at offset q*32.
    const size_t out_base = (((size_t)b * HALF_ + i1) * HALF_ + i2) * 128 + (size_t)cv * 4;
    *reinterpret_cast<float4*>(out + out_base)      = ll;  // LL
    *reinterpret_cast<float4*>(out + out_base + 32) = lh;  // LH
    *reinterpret_cast<float4*>(out + out_base + 64) = hl;  // HL
    *reinterpret_cast<float4*>(out + out_base + 96) = hh;  // HH
}

extern "C" void kernel_launch(void* const* d_in, const int* in_sizes, int n_in,
                              void* d_out, int out_size, void* d_ws, size_t ws_size,
                              hipStream_t stream) {
    const float* x   = (const float*)d_in[0];   // (8,512,512,32) f32
    float*       out = (float*)d_out;           // (8,256,256,128) f32

    const int total_threads = B_ * HALF_ * HALF_ * (C_ / 4);  // 4,194,304
    const int block = 256;
    const int grid  = total_threads / block;                  // 16384

    dwt2d_haar<<<grid, block, 0, stream>>>(x, out);
}